// Round 5
// baseline (306.538 us; speedup 1.0000x reference)
//
#include <hip/hip_runtime.h>
#include <hip/hip_fp16.h>
#include <hip/hip_cooperative_groups.h>

namespace cg = cooperative_groups;

#define N_NODES 50000
#define N_EDGES 800000
#define D 64
#define BLOCK 256
#define GRID 512

#define NBIN 256      // bins over node space
#define BINW 196      // nodes per bin; 256*196 = 50176 >= 50000
#define BCAP 3584     // per-bin capacity; Binom mean 3136, sd 56 -> +8 sigma
#define EPBF 1563     // edges per block, fused: 512*1563 = 800256 >= 800000
#define KITF 7        // ceil(EPBF/BLOCK)
#define STAGEB 1568   // >= EPBF
#define RNODES 98     // nodes per block in phase B (512*98 = 50176)
#define QCAP 1920     // row-sorted queue; mean 1568, sd 40 -> +8.8 sigma

// fallback-path sizing (R4 structure, used only if cooperative launch fails)
#define EPB 4096
#define NBINBLK 196
#define PREBLK 196
#define SUBS_F 4
#define RN_F 49
#define QCAP_F 1024

// ============================ fused cooperative ============================
// Phase A (all 512 blocks): (1) counting-sort 1563 edges into 256 node-range
// bins via LDS, write contiguous runs (no 4B scatter write-amp); (2) MLP
// precompute, one node per lane (t<98), acc[64] register accumulators, zero
// cross-lane ops. __threadfence + grid.sync (device scope, cross-XCD — G16).
// Phase B: each block aggregates 98 rows: stage bin run in LDS while
// histogramming, 128-wide scan, row-sorted LDS queue, 16x 16-lane-stream
// drain with 8-deep pipelined 128B M16 gathers. No FP atomics anywhere.
__global__ __launch_bounds__(BLOCK) void fused_kernel(
    const float* __restrict__ h, const float* __restrict__ x,
    const int* __restrict__ eidx,
    const float* __restrict__ Wh, const float* __restrict__ bh,
    const float* __restrict__ Wx, const float* __restrict__ bx,
    __half2* __restrict__ M16, float4* __restrict__ px,
    int* __restrict__ bins, int* __restrict__ gcur,
    float* __restrict__ out) {
  __shared__ union {
    struct {
      int cnt[NBIN], ssc[NBIN], start[NBIN], cur[NBIN], gbase[NBIN];
      int stage[STAGEB];
    } bl;                              // 11.4 KB
    struct {
      int stage2[BCAP];                // bin run staged in LDS
      int qs[QCAP];
      int sc[128];
      int hist[RNODES], rcur[RNODES];
      int rstart[RNODES + 1];
    } ag;                              // 23.7 KB
  } S;

  const int b = blockIdx.x;
  const int t = threadIdx.x;

  // ---------------- phase A1: binning ----------------
  S.bl.cnt[t] = 0;
  __syncthreads();
  const int ebase = b * EPBF;
  const int eend = min(ebase + EPBF, N_EDGES);
#pragma unroll
  for (int k = 0; k < KITF; ++k) {     // pass 1: histogram
    int e = ebase + k * BLOCK + t;
    if (e < eend) {
      int row = eidx[e];
      if ((unsigned)row < N_NODES) atomicAdd(&S.bl.cnt[row / BINW], 1);
    }
  }
  __syncthreads();
  S.bl.ssc[t] = S.bl.cnt[t];           // inclusive scan over 256 bins
  __syncthreads();
  for (int off = 1; off < NBIN; off <<= 1) {
    int v = (t >= off) ? S.bl.ssc[t - off] : 0;
    __syncthreads();
    S.bl.ssc[t] += v;
    __syncthreads();
  }
  {
    int ex = S.bl.ssc[t] - S.bl.cnt[t];
    S.bl.start[t] = ex;
    S.bl.cur[t] = ex;
    S.bl.gbase[t] = S.bl.cnt[t] ? atomicAdd(&gcur[t], S.bl.cnt[t]) : 0;
  }
  __syncthreads();
#pragma unroll
  for (int k = 0; k < KITF; ++k) {     // pass 2: scatter into LDS stage
    int e = ebase + k * BLOCK + t;
    if (e < eend) {
      int row = eidx[e];
      int col = eidx[N_EDGES + e];
      if ((unsigned)row < N_NODES && (unsigned)col < N_NODES) {
        int bb = row / BINW;
        int pos = atomicAdd(&S.bl.cur[bb], 1);
        S.bl.stage[pos] = (bb << 24) | ((row - bb * BINW) << 16) | col;
      }
    }
  }
  __syncthreads();
  {
    const int total = S.bl.ssc[NBIN - 1];
    for (int idx = t; idx < total; idx += BLOCK) {  // coalesced run copy-out
      int e = S.bl.stage[idx];
      int bb = ((unsigned)e) >> 24;
      int dst = S.bl.gbase[bb] + (idx - S.bl.start[bb]);
      if (dst < BCAP) bins[(size_t)bb * BCAP + dst] = e;
    }
  }

  // ---------------- phase A2: MLP precompute (one node per lane) -------
  {
    const int i = b * RNODES + t;      // t<98 handles one node
    if (t < RNODES && i < N_NODES) {
      const float4* __restrict__ h4 = (const float4*)(h + (size_t)i * D);
      const float4* __restrict__ Wx4 = (const float4*)Wx;
      float acc[D];
#pragma unroll
      for (int d = 0; d < D; ++d) acc[d] = bh[d];
      float wx = bx[0];
      for (int q = 0; q < D / 4; ++q) {
        float4 hv = h4[q];
        float4 wxv = Wx4[q];           // uniform
        wx = fmaf(hv.x, wxv.x, fmaf(hv.y, wxv.y,
             fmaf(hv.z, wxv.z, fmaf(hv.w, wxv.w, wx))));
#pragma unroll
        for (int r = 0; r < 4; ++r) {
          float hk = (r == 0) ? hv.x : (r == 1) ? hv.y : (r == 2) ? hv.z : hv.w;
          const float4* wr4 = (const float4*)(Wh + (q * 4 + r) * D);  // uniform
#pragma unroll
          for (int dq = 0; dq < D / 4; ++dq) {
            float4 wv = wr4[dq];
            acc[4 * dq + 0] = fmaf(hk, wv.x, acc[4 * dq + 0]);
            acc[4 * dq + 1] = fmaf(hk, wv.y, acc[4 * dq + 1]);
            acc[4 * dq + 2] = fmaf(hk, wv.z, acc[4 * dq + 2]);
            acc[4 * dq + 3] = fmaf(hk, wv.w, acc[4 * dq + 3]);
          }
        }
      }
      __half2 hh[D / 2];
#pragma unroll
      for (int j = 0; j < D / 2; ++j)
        hh[j] = __floats2half2_rn(fmaxf(acc[2 * j], 0.0f),
                                  fmaxf(acc[2 * j + 1], 0.0f));
      float4* mrow = (float4*)(M16 + (size_t)i * 32);
      const float4* hhp = (const float4*)hh;
#pragma unroll
      for (int q = 0; q < 8; ++q) mrow[q] = hhp[q];
      float w = fmaxf(wx, 0.0f);
      px[i] = make_float4(w, w * x[(size_t)i * 3 + 0],
                          w * x[(size_t)i * 3 + 1],
                          w * x[(size_t)i * 3 + 2]);
    }
  }

  __threadfence();                     // device-scope release (cross-XCD)
  cg::this_grid().sync();
  __threadfence();                     // acquire side

  // ---------------- phase B: aggregate 98 rows ----------------
  {
    const int bin = b >> 1, sub = b & 1;
    const int lbase = sub * RNODES;
    const int gb = bin * BINW + lbase;
    const int R = min(RNODES, N_NODES - gb);
    if (R > 0) {                       // block 511 skips (uniform per block)
      if (t < RNODES) S.ag.hist[t] = 0;
      __syncthreads();
      const int n = min(gcur[bin], BCAP);
      const int* bs = bins + (size_t)bin * BCAP;
      for (int ii = t; ii < n; ii += BLOCK) {  // pass 1: stage + histogram
        int e = bs[ii];
        S.ag.stage2[ii] = e;
        unsigned dd = (unsigned)((e >> 16) & 0xff) - (unsigned)lbase;
        if (dd < (unsigned)R) atomicAdd(&S.ag.hist[dd], 1);
      }
      __syncthreads();
      if (t < 128) S.ag.sc[t] = (t < R) ? S.ag.hist[t] : 0;
      __syncthreads();
      for (int off = 1; off < 128; off <<= 1) {   // 128-wide inclusive scan
        int v = (t < 128 && t >= off) ? S.ag.sc[t - off] : 0;
        __syncthreads();
        if (t < 128) S.ag.sc[t] += v;
        __syncthreads();
      }
      if (t == 0) S.ag.rstart[0] = 0;
      if (t < R) {
        S.ag.rstart[t + 1] = S.ag.sc[t];
        S.ag.rcur[t] = S.ag.sc[t] - S.ag.hist[t];
      }
      __syncthreads();
      for (int ii = t; ii < n; ii += BLOCK) {  // pass 2: row-sorted scatter
        int e = S.ag.stage2[ii];
        unsigned dd = (unsigned)((e >> 16) & 0xff) - (unsigned)lbase;
        if (dd < (unsigned)R) {
          int pos = atomicAdd(&S.ag.rcur[dd], 1);
          if (pos < QCAP) S.ag.qs[pos] = e;
        }
      }
      __syncthreads();

      const float* pxf = (const float*)px;
      const float2* M2 = (const float2*)M16;   // 16 float2 per 128B row
      const int l16 = t & 15;
      const int stream = t >> 4;       // 0..15
      const int wbase = t & 48;        // stream base lane within wave
      const size_t xb = (size_t)N_NODES * D;

      for (int rr = stream; rr < R; rr += 16) {
        int beg = min(S.ag.rstart[rr], QCAP);
        int end = min(S.ag.rstart[rr + 1], QCAP);
        float a0 = 0.f, a1 = 0.f, a2 = 0.f, a3 = 0.f, ps = 0.f;
        for (int qi = beg; qi < end; qi += 8) {  // 8-deep load pipeline
          float2 g[8];
          float pv[8];
          bool val[8];
#pragma unroll
          for (int j = 0; j < 8; ++j) {
            int idx = qi + j;
            val[j] = idx < end;
            int e = S.ag.qs[val[j] ? idx : beg];
            int c = e & 0xffff;
            pv[j] = 0.f;
            if (val[j]) {
              g[j] = M2[(size_t)c * 16 + l16];   // 8B/lane, 128B/row/stream
              if (l16 < 4) pv[j] = pxf[c * 4 + l16];
            }
          }
#pragma unroll
          for (int j = 0; j < 8; ++j)
            if (val[j]) {
              const __half2* hp = (const __half2*)&g[j];
              float2 f0 = __half22float2(hp[0]);
              float2 f1 = __half22float2(hp[1]);
              a0 += f0.x; a1 += f0.y; a2 += f1.x; a3 += f1.y;
              ps += pv[j];
            }
        }
        int gn = gb + rr;
        float4 hvv = ((const float4*)h)[(size_t)gn * 16 + l16];
        ((float4*)out)[(size_t)gn * 16 + l16] =
            make_float4(hvv.x + a0, hvv.y + a1, hvv.z + a2, hvv.w + a3);
        float W = __shfl(ps, wbase);              // lane0: sum w
        float pc = __shfl(ps, wbase + l16 + 1);   // lanes 1..3: sum w*x_c
        if (l16 < 3)
          out[xb + (size_t)gn * 3 + l16] =
              fmaf(x[(size_t)gn * 3 + l16], 1.0f + W, -pc);
      }
    }
  }
}

// ================== fallback: R4 two-kernel path ==========================
__global__ __launch_bounds__(BLOCK) void pre_bin_kernel(
    const float* __restrict__ h, const float* __restrict__ x,
    const int* __restrict__ eidx,
    const float* __restrict__ Wh, const float* __restrict__ bh,
    const float* __restrict__ Wx, const float* __restrict__ bx,
    __half2* __restrict__ M16, float4* __restrict__ px,
    int* __restrict__ bins, int* __restrict__ gcur) {
  const unsigned b = blockIdx.x;
  if (b < NBINBLK) {
    __shared__ int cnt[NBIN], ssc[NBIN], start[NBIN], cur[NBIN], gbase[NBIN];
    __shared__ int stage[EPB];
    const int t = threadIdx.x;
    cnt[t] = 0;
    __syncthreads();
    const int base = (int)b * EPB;
#pragma unroll 4
    for (int k = 0; k < EPB / BLOCK; ++k) {
      int e = base + k * BLOCK + t;
      if (e < N_EDGES) {
        int row = eidx[e];
        if ((unsigned)row < N_NODES) atomicAdd(&cnt[row / BINW], 1);
      }
    }
    __syncthreads();
    ssc[t] = cnt[t];
    __syncthreads();
    for (int off = 1; off < NBIN; off <<= 1) {
      int v = (t >= off) ? ssc[t - off] : 0;
      __syncthreads();
      ssc[t] += v;
      __syncthreads();
    }
    int ex = ssc[t] - cnt[t];
    start[t] = ex; cur[t] = ex;
    gbase[t] = cnt[t] ? atomicAdd(&gcur[t], cnt[t]) : 0;
    __syncthreads();
#pragma unroll 4
    for (int k = 0; k < EPB / BLOCK; ++k) {
      int e = base + k * BLOCK + t;
      if (e < N_EDGES) {
        int row = eidx[e];
        int col = eidx[N_EDGES + e];
        if ((unsigned)row < N_NODES && (unsigned)col < N_NODES) {
          int bb = row / BINW;
          int pos = atomicAdd(&cur[bb], 1);
          stage[pos] = (bb << 24) | ((row - bb * BINW) << 16) | col;
        }
      }
    }
    __syncthreads();
    const int total = ssc[NBIN - 1];
    for (int idx = t; idx < total; idx += BLOCK) {
      int e = stage[idx];
      int bb = ((unsigned)e) >> 24;
      int dst = gbase[bb] + (idx - start[bb]);
      if (dst < BCAP) bins[(size_t)bb * BCAP + dst] = e;
    }
    return;
  }
  const int pid = (int)b - NBINBLK;
  const int i = pid * BLOCK + threadIdx.x;
  if (i >= N_NODES) return;
  const float4* __restrict__ h4 = (const float4*)(h + (size_t)i * D);
  const float4* __restrict__ Wx4 = (const float4*)Wx;
  float acc[D];
#pragma unroll
  for (int d = 0; d < D; ++d) acc[d] = bh[d];
  float wx = bx[0];
  for (int q = 0; q < D / 4; ++q) {
    float4 hv = h4[q];
    float4 wxv = Wx4[q];
    wx = fmaf(hv.x, wxv.x, fmaf(hv.y, wxv.y, fmaf(hv.z, wxv.z,
         fmaf(hv.w, wxv.w, wx))));
#pragma unroll
    for (int r = 0; r < 4; ++r) {
      float hk = (r == 0) ? hv.x : (r == 1) ? hv.y : (r == 2) ? hv.z : hv.w;
      const float4* wr4 = (const float4*)(Wh + (q * 4 + r) * D);
#pragma unroll
      for (int dq = 0; dq < D / 4; ++dq) {
        float4 wv = wr4[dq];
        acc[4 * dq + 0] = fmaf(hk, wv.x, acc[4 * dq + 0]);
        acc[4 * dq + 1] = fmaf(hk, wv.y, acc[4 * dq + 1]);
        acc[4 * dq + 2] = fmaf(hk, wv.z, acc[4 * dq + 2]);
        acc[4 * dq + 3] = fmaf(hk, wv.w, acc[4 * dq + 3]);
      }
    }
  }
  __half2 hh[D / 2];
#pragma unroll
  for (int j = 0; j < D / 2; ++j)
    hh[j] = __floats2half2_rn(fmaxf(acc[2 * j], 0.0f),
                              fmaxf(acc[2 * j + 1], 0.0f));
  float4* mrow = (float4*)(M16 + (size_t)i * 32);
  const float4* hhp = (const float4*)hh;
#pragma unroll
  for (int q = 0; q < 8; ++q) mrow[q] = hhp[q];
  float w = fmaxf(wx, 0.0f);
  px[i] = make_float4(w, w * x[(size_t)i * 3 + 0],
                      w * x[(size_t)i * 3 + 1], w * x[(size_t)i * 3 + 2]);
}

__global__ __launch_bounds__(256) void agg_kernel(
    const float* __restrict__ h, const float* __restrict__ x,
    const int* __restrict__ bins, const int* __restrict__ gcur,
    const __half2* __restrict__ M16, const float4* __restrict__ px,
    float* __restrict__ out) {
  __shared__ int qs[QCAP_F];
  __shared__ int hist[RN_F], rstart[RN_F + 1], rcur[RN_F];
  const int t = threadIdx.x;
  const int bin = blockIdx.x >> 2, sub = blockIdx.x & 3;
  const int lbase = sub * RN_F;
  const int gb = bin * BINW + lbase;
  const int R = min(RN_F, N_NODES - gb);
  if (R <= 0) return;
  if (t < RN_F) hist[t] = 0;
  __syncthreads();
  const int n = min(gcur[bin], BCAP);
  const int* bs = bins + (size_t)bin * BCAP;
  for (int i = t; i < n; i += 256) {
    int e = bs[i];
    unsigned dd = (unsigned)((e >> 16) & 0xff) - (unsigned)lbase;
    if (dd < (unsigned)R) atomicAdd(&hist[dd], 1);
  }
  __syncthreads();
  if (t < 64) {
    int myh = (t < R) ? hist[t] : 0;
    int v = myh;
#pragma unroll
    for (int off = 1; off < 64; off <<= 1) {
      int u = __shfl_up(v, off);
      if (t >= off) v += u;
    }
    if (t == 0) rstart[0] = 0;
    if (t < R) { rstart[t + 1] = v; rcur[t] = v - myh; }
  }
  __syncthreads();
  for (int i = t; i < n; i += 256) {
    int e = bs[i];
    unsigned dd = (unsigned)((e >> 16) & 0xff) - (unsigned)lbase;
    if (dd < (unsigned)R) {
      int pos = atomicAdd(&rcur[dd], 1);
      if (pos < QCAP_F) qs[pos] = e;
    }
  }
  __syncthreads();
  const float* pxf = (const float*)px;
  const float2* M2 = (const float2*)M16;
  const int l16 = t & 15;
  const int stream = t >> 4;
  const int wbase = t & 48;
  const size_t xb = (size_t)N_NODES * D;
  for (int rr = stream; rr < R; rr += 16) {
    int beg = min(rstart[rr], QCAP_F);
    int end = min(rstart[rr + 1], QCAP_F);
    float a0 = 0.f, a1 = 0.f, a2 = 0.f, a3 = 0.f, ps = 0.f;
    for (int qi = beg; qi < end; qi += 8) {
      float2 g[8]; float pv[8]; bool val[8];
#pragma unroll
      for (int j = 0; j < 8; ++j) {
        int idx = qi + j;
        val[j] = idx < end;
        int e = qs[val[j] ? idx : beg];
        int c = e & 0xffff;
        pv[j] = 0.f;
        if (val[j]) {
          g[j] = M2[(size_t)c * 16 + l16];
          if (l16 < 4) pv[j] = pxf[c * 4 + l16];
        }
      }
#pragma unroll
      for (int j = 0; j < 8; ++j)
        if (val[j]) {
          const __half2* hp = (const __half2*)&g[j];
          float2 f0 = __half22float2(hp[0]);
          float2 f1 = __half22float2(hp[1]);
          a0 += f0.x; a1 += f0.y; a2 += f1.x; a3 += f1.y;
          ps += pv[j];
        }
    }
    int gn = gb + rr;
    float4 hvv = ((const float4*)h)[(size_t)gn * 16 + l16];
    ((float4*)out)[(size_t)gn * 16 + l16] =
        make_float4(hvv.x + a0, hvv.y + a1, hvv.z + a2, hvv.w + a3);
    float W = __shfl(ps, wbase);
    float pc = __shfl(ps, wbase + l16 + 1);
    if (l16 < 3)
      out[xb + (size_t)gn * 3 + l16] =
          fmaf(x[(size_t)gn * 3 + l16], 1.0f + W, -pc);
  }
}

// -------- ws-too-small fallback (atomic path) --------
__global__ __launch_bounds__(256) void init_out_kernel(
    const float* __restrict__ h, const float* __restrict__ x,
    float* __restrict__ out) {
  const int NH4 = N_NODES * D / 4;
  const int NT4 = (N_NODES * D + N_NODES * 3) / 4;
  int i = blockIdx.x * 256 + threadIdx.x;
  if (i >= NT4) return;
  float4 v;
  if (i < NH4) v = ((const float4*)h)[i];
  else         v = ((const float4*)x)[i - NH4];
  ((float4*)out)[i] = v;
}

__global__ __launch_bounds__(256) void edge_kernel(
    const float* __restrict__ h, const float* __restrict__ x,
    const int* __restrict__ eidx,
    const float* __restrict__ Wh, const float* __restrict__ bh,
    const float* __restrict__ Wx, const float* __restrict__ bx,
    float* __restrict__ out) {
  int e = blockIdx.x * 256 + threadIdx.x;
  if (e >= N_EDGES) return;
  int row = eidx[e];
  int col = eidx[N_EDGES + e];
  if ((unsigned)row >= N_NODES || (unsigned)col >= N_NODES) return;
  const float* hj = h + (size_t)col * D;
  float acc[D];
#pragma unroll
  for (int dd = 0; dd < D; ++dd) acc[dd] = bh[dd];
  float wsum = bx[0];
#pragma unroll 2
  for (int kg = 0; kg < D / 4; ++kg) {
    float4 hv = *(const float4*)(hj + kg * 4);
#pragma unroll
    for (int j = 0; j < 4; ++j) {
      float hk = (j == 0) ? hv.x : (j == 1) ? hv.y : (j == 2) ? hv.z : hv.w;
      int k = kg * 4 + j;
      wsum = fmaf(hk, Wx[k], wsum);
      const float* wrow = Wh + k * D;
#pragma unroll
      for (int dd = 0; dd < D; ++dd) acc[dd] = fmaf(hk, wrow[dd], acc[dd]);
    }
  }
  float* outh = out + (size_t)row * D;
#pragma unroll
  for (int dd = 0; dd < D; ++dd) atomicAdd(&outh[dd], fmaxf(acc[dd], 0.0f));
  float w = fmaxf(wsum, 0.0f);
  float* outx = out + (size_t)N_NODES * D + (size_t)row * 3;
  const float* xr = x + (size_t)row * 3;
  const float* xc = x + (size_t)col * 3;
#pragma unroll
  for (int c = 0; c < 3; ++c) atomicAdd(&outx[c], (xr[c] - xc[c]) * w);
}

// ---------------- launch ----------------
extern "C" void kernel_launch(void* const* d_in, const int* in_sizes, int n_in,
                              void* d_out, int out_size, void* d_ws, size_t ws_size,
                              hipStream_t stream) {
  const float* h    = (const float*)d_in[0];
  const float* x    = (const float*)d_in[1];
  const int*   eidx = (const int*)d_in[2];   // int64 in reference, int32 here
  const float* Wh   = (const float*)d_in[3];
  const float* bh   = (const float*)d_in[4];
  const float* Wx   = (const float*)d_in[5];
  const float* bx   = (const float*)d_in[6];
  float* out = (float*)d_out;

  size_t need = (size_t)N_NODES * D * 2 + (size_t)N_NODES * 16 +
                (size_t)NBIN * BCAP * 4 + 1024;

  if (ws_size < need) {  // fallback: atomic path (correct, slow)
    const int NT4 = (N_NODES * D + N_NODES * 3) / 4;
    init_out_kernel<<<(NT4 + 255) / 256, 256, 0, stream>>>(h, x, out);
    edge_kernel<<<(N_EDGES + 255) / 256, 256, 0, stream>>>(
        h, x, eidx, Wh, bh, Wx, bx, out);
    return;
  }

  __half2* M16 = (__half2*)d_ws;
  float4*  px  = (float4*)((char*)d_ws + (size_t)N_NODES * D * 2);
  int*     bins = (int*)((char*)px + (size_t)N_NODES * 16);
  int*     gcur = bins + (size_t)NBIN * BCAP;

  hipMemsetAsync(gcur, 0, NBIN * sizeof(int), stream);

  void* kargs[] = {(void*)&h, (void*)&x, (void*)&eidx, (void*)&Wh,
                   (void*)&bh, (void*)&Wx, (void*)&bx, (void*)&M16,
                   (void*)&px, (void*)&bins, (void*)&gcur, (void*)&out};
  hipError_t rc = hipLaunchCooperativeKernel(
      reinterpret_cast<void*>(fused_kernel), dim3(GRID), dim3(BLOCK),
      kargs, 0, stream);
  if (rc != hipSuccess) {              // cooperative refused -> two-kernel path
    pre_bin_kernel<<<NBINBLK + PREBLK, BLOCK, 0, stream>>>(
        h, x, eidx, Wh, bh, Wx, bx, M16, px, bins, gcur);
    agg_kernel<<<NBIN * SUBS_F, 256, 0, stream>>>(
        h, x, bins, gcur, M16, px, out);
  }
}

// Round 6
// 140.312 us; speedup vs baseline: 2.1847x; 2.1847x over previous
//
#include <hip/hip_runtime.h>
#include <hip/hip_fp16.h>

#define N_NODES 50000
#define N_EDGES 800000
#define D 64
#define BLOCK 256

#define NBIN 256      // bins over node space
#define BINW 196      // nodes per bin; 256*196 = 50176 >= 50000
#define BCAP 3584     // per-bin capacity; Binom mean 3136, sd 56 -> +8 sigma
#define EPB 2048      // edges per binning block (halved vs R4: 2x concurrency)
#define KIT 8         // EPB/BLOCK
#define NBINBLK 391   // ceil(800000/2048)
#define PREBLK 196    // MLP blocks, 256 nodes each
#define SUBS 4        // agg sub-blocks per bin
#define RNODES 49     // rows per agg block
#define QCAP 1024     // row-sorted queue; mean 784, sd 28 -> +8.5 sigma
#define HALF_COL 25000
#define ROWS_PS 4     // max rows per 16-lane stream: ceil(49/16)

// ---------- merged binning | precompute ------------------------------------
// Binning (blocks [0,391)): counting-sort 2048 edges into 256 node-range bins
// in LDS, write ~32B contiguous runs. Precompute (blocks [391,587)): one node
// per lane, acc[64] register MLP, zero cross-lane ops (R4 structure).
__global__ __launch_bounds__(BLOCK) void pre_bin_kernel(
    const float* __restrict__ h, const float* __restrict__ x,
    const int* __restrict__ eidx,
    const float* __restrict__ Wh, const float* __restrict__ bh,
    const float* __restrict__ Wx, const float* __restrict__ bx,
    __half2* __restrict__ M16, float4* __restrict__ px,
    int* __restrict__ bins, int* __restrict__ gcur) {
  const unsigned b = blockIdx.x;

  if (b < NBINBLK) {                   // ---- binning path ----
    __shared__ int cnt[NBIN], ssc[NBIN], start[NBIN], cur[NBIN], gbase[NBIN];
    __shared__ int stage[EPB];         // 8 KB
    const int t = threadIdx.x;
    cnt[t] = 0;
    __syncthreads();
    const int base = (int)b * EPB;
#pragma unroll
    for (int k = 0; k < KIT; ++k) {    // pass 1: histogram
      int e = base + k * BLOCK + t;
      if (e < N_EDGES) {
        int row = eidx[e];
        if ((unsigned)row < N_NODES) atomicAdd(&cnt[row / BINW], 1);
      }
    }
    __syncthreads();
    ssc[t] = cnt[t];                   // inclusive prefix scan over 256 bins
    __syncthreads();
    for (int off = 1; off < NBIN; off <<= 1) {
      int v = (t >= off) ? ssc[t - off] : 0;
      __syncthreads();
      ssc[t] += v;
      __syncthreads();
    }
    int ex = ssc[t] - cnt[t];
    start[t] = ex;
    cur[t] = ex;
    gbase[t] = cnt[t] ? atomicAdd(&gcur[t], cnt[t]) : 0;  // one global atomic/bin
    __syncthreads();
#pragma unroll
    for (int k = 0; k < KIT; ++k) {    // pass 2: scatter into LDS stage
      int e = base + k * BLOCK + t;
      if (e < N_EDGES) {
        int row = eidx[e];
        int col = eidx[N_EDGES + e];
        if ((unsigned)row < N_NODES && (unsigned)col < N_NODES) {
          int bb = row / BINW;
          int pos = atomicAdd(&cur[bb], 1);
          stage[pos] = (bb << 24) | ((row - bb * BINW) << 16) | col;
        }
      }
    }
    __syncthreads();
    const int total = ssc[NBIN - 1];
    for (int idx = t; idx < total; idx += BLOCK) {  // coalesced run copy-out
      int e = stage[idx];
      int bb = ((unsigned)e) >> 24;
      int dst = gbase[bb] + (idx - start[bb]);
      if (dst < BCAP) bins[(size_t)bb * BCAP + dst] = e;
    }
    return;
  }

  // ---- precompute path: one node per lane, register accumulators ----
  const int pid = (int)b - NBINBLK;    // 0..195
  const int i = pid * BLOCK + threadIdx.x;
  if (i >= N_NODES) return;

  const float4* __restrict__ h4 = (const float4*)(h + (size_t)i * D);
  const float4* __restrict__ Wx4 = (const float4*)Wx;

  float acc[D];
#pragma unroll
  for (int d = 0; d < D; ++d) acc[d] = bh[d];
  float wx = bx[0];

  for (int q = 0; q < D / 4; ++q) {    // NOT unrolled: keeps code ~256 fma
    float4 hv = h4[q];
    float4 wxv = Wx4[q];               // wave-uniform
    wx = fmaf(hv.x, wxv.x, fmaf(hv.y, wxv.y, fmaf(hv.z, wxv.z,
         fmaf(hv.w, wxv.w, wx))));
#pragma unroll
    for (int r = 0; r < 4; ++r) {
      float hk = (r == 0) ? hv.x : (r == 1) ? hv.y : (r == 2) ? hv.z : hv.w;
      const float4* wr4 = (const float4*)(Wh + (q * 4 + r) * D);  // uniform row
#pragma unroll
      for (int dq = 0; dq < D / 4; ++dq) {
        float4 wv = wr4[dq];
        acc[4 * dq + 0] = fmaf(hk, wv.x, acc[4 * dq + 0]);
        acc[4 * dq + 1] = fmaf(hk, wv.y, acc[4 * dq + 1]);
        acc[4 * dq + 2] = fmaf(hk, wv.z, acc[4 * dq + 2]);
        acc[4 * dq + 3] = fmaf(hk, wv.w, acc[4 * dq + 3]);
      }
    }
  }

  __half2 hh[D / 2];
#pragma unroll
  for (int j = 0; j < D / 2; ++j)
    hh[j] = __floats2half2_rn(fmaxf(acc[2 * j], 0.0f),
                              fmaxf(acc[2 * j + 1], 0.0f));
  float4* mrow = (float4*)(M16 + (size_t)i * 32);
  const float4* hhp = (const float4*)hh;
#pragma unroll
  for (int q = 0; q < 8; ++q) mrow[q] = hhp[q];  // per-lane 128B row

  float w = fmaxf(wx, 0.0f);
  px[i] = make_float4(w, w * x[(size_t)i * 3 + 0],
                      w * x[(size_t)i * 3 + 1],
                      w * x[(size_t)i * 3 + 2]);
}

// ---------- aggregate: col-half phased drain for L2 residency --------------
// Sort key = (row_local, col>=25000). All 1024 blocks drain half 0 first,
// then half 1 -> the active M16 half (3.2MB) + px (0.8MB) fit the 4MB
// per-XCD L2, so the 102MB gather is served at L2 BW instead of L3 latency
// (R5 counters: gather was the pole at ~2.9 TB/s effective). Stream's <=4
// row accumulators stay in registers across both halves (static unroll).
__global__ __launch_bounds__(256) void agg_kernel(
    const float* __restrict__ h, const float* __restrict__ x,
    const int* __restrict__ bins, const int* __restrict__ gcur,
    const __half2* __restrict__ M16, const float4* __restrict__ px,
    float* __restrict__ out) {
  __shared__ int stage2[BCAP];         // 14 KB: bin run staged in LDS
  __shared__ int qs[QCAP];             // 4 KB
  __shared__ int sc[128];
  __shared__ int hist[2 * RNODES], rcur[2 * RNODES];
  __shared__ int rstart[2 * RNODES + 1];

  const int t = threadIdx.x;
  const int bin = blockIdx.x >> 2, sub = blockIdx.x & 3;
  const int lbase = sub * RNODES;      // row_local base within bin
  const int gb = bin * BINW + lbase;   // first global node
  const int R = min(RNODES, N_NODES - gb);
  if (R <= 0) return;

  if (t < 2 * RNODES) hist[t] = 0;
  __syncthreads();

  const int n = min(gcur[bin], BCAP);
  const int* bs = bins + (size_t)bin * BCAP;
  for (int i = t; i < n; i += 256) {   // pass 1: stage + histogram
    int e = bs[i];
    stage2[i] = e;
    unsigned dd = (unsigned)((e >> 16) & 0xff) - (unsigned)lbase;
    if (dd < (unsigned)R) {
      int kk = (int)dd * 2 + ((e & 0xffff) >= HALF_COL);
      atomicAdd(&hist[kk], 1);
    }
  }
  __syncthreads();
  if (t < 128) sc[t] = (t < 2 * R) ? hist[t] : 0;
  __syncthreads();
  for (int off = 1; off < 128; off <<= 1) {  // 128-wide inclusive scan
    int v = (t < 128 && t >= off) ? sc[t - off] : 0;
    __syncthreads();
    if (t < 128) sc[t] += v;
    __syncthreads();
  }
  if (t == 0) rstart[0] = 0;
  if (t < 2 * R) {
    rstart[t + 1] = sc[t];
    rcur[t] = sc[t] - hist[t];
  }
  __syncthreads();
  for (int i = t; i < n; i += 256) {   // pass 2: (row,half)-sorted scatter
    int e = stage2[i];
    unsigned dd = (unsigned)((e >> 16) & 0xff) - (unsigned)lbase;
    if (dd < (unsigned)R) {
      int kk = (int)dd * 2 + ((e & 0xffff) >= HALF_COL);
      int pos = atomicAdd(&rcur[kk], 1);
      if (pos < QCAP) qs[pos] = e;
    }
  }
  __syncthreads();

  const float* pxf = (const float*)px;
  const float2* M2 = (const float2*)M16;   // 16 float2 per 128B row
  const int l16 = t & 15;              // lane within 16-lane stream
  const int stream = t >> 4;           // 0..15
  const int wbase = t & 48;            // stream's base lane within the wave
  const size_t xb = (size_t)N_NODES * D;

  float ac[ROWS_PS][4];
  float ps[ROWS_PS];
#pragma unroll
  for (int k = 0; k < ROWS_PS; ++k) {
    ac[k][0] = ac[k][1] = ac[k][2] = ac[k][3] = 0.f;
    ps[k] = 0.f;
  }

  for (int hf = 0; hf < 2; ++hf) {     // phased drain: half 0 then half 1
#pragma unroll
    for (int k = 0; k < ROWS_PS; ++k) {
      int rr = stream + 16 * k;
      if (rr < R) {
        int beg = min(rstart[2 * rr + hf], QCAP);
        int end = min(rstart[2 * rr + hf + 1], QCAP);
        for (int qi = beg; qi < end; qi += 8) {   // 8-deep load pipeline
          float2 g[8];
          float pv[8];
          bool val[8];
#pragma unroll
          for (int j = 0; j < 8; ++j) {
            int idx = qi + j;
            val[j] = idx < end;
            int e = qs[val[j] ? idx : beg];       // LDS broadcast per stream
            int c = e & 0xffff;
            pv[j] = 0.f;
            if (val[j]) {
              g[j] = M2[(size_t)c * 16 + l16];    // 8B/lane, 128B row/stream
              if (l16 < 4) pv[j] = pxf[c * 4 + l16];
            }
          }
#pragma unroll
          for (int j = 0; j < 8; ++j)
            if (val[j]) {
              const __half2* hp = (const __half2*)&g[j];
              float2 f0 = __half22float2(hp[0]);
              float2 f1 = __half22float2(hp[1]);
              ac[k][0] += f0.x; ac[k][1] += f0.y;
              ac[k][2] += f1.x; ac[k][3] += f1.y;
              ps[k] += pv[j];
            }
        }
      }
    }
  }

#pragma unroll
  for (int k = 0; k < ROWS_PS; ++k) {  // epilogue: exclusive, coalesced
    int rr = stream + 16 * k;
    if (rr < R) {
      int gn = gb + rr;
      float4 hvv = ((const float4*)h)[(size_t)gn * 16 + l16];
      ((float4*)out)[(size_t)gn * 16 + l16] =
          make_float4(hvv.x + ac[k][0], hvv.y + ac[k][1],
                      hvv.z + ac[k][2], hvv.w + ac[k][3]);
      float W = __shfl(ps[k], wbase);            // stream lane0: sum w
      float pc = __shfl(ps[k], wbase + l16 + 1); // lanes 1..3: sum w*x_c
      if (l16 < 3)
        out[xb + (size_t)gn * 3 + l16] =
            fmaf(x[(size_t)gn * 3 + l16], 1.0f + W, -pc);
    }
  }
}

// ---------------- fallback (atomic path, used only if ws too small) --------

__global__ __launch_bounds__(256) void init_out_kernel(
    const float* __restrict__ h, const float* __restrict__ x,
    float* __restrict__ out) {
  const int NH4 = N_NODES * D / 4;
  const int NT4 = (N_NODES * D + N_NODES * 3) / 4;
  int i = blockIdx.x * 256 + threadIdx.x;
  if (i >= NT4) return;
  float4 v;
  if (i < NH4) v = ((const float4*)h)[i];
  else         v = ((const float4*)x)[i - NH4];
  ((float4*)out)[i] = v;
}

__global__ __launch_bounds__(256) void edge_kernel(
    const float* __restrict__ h, const float* __restrict__ x,
    const int* __restrict__ eidx,
    const float* __restrict__ Wh, const float* __restrict__ bh,
    const float* __restrict__ Wx, const float* __restrict__ bx,
    float* __restrict__ out) {
  int e = blockIdx.x * 256 + threadIdx.x;
  if (e >= N_EDGES) return;
  int row = eidx[e];
  int col = eidx[N_EDGES + e];
  if ((unsigned)row >= N_NODES || (unsigned)col >= N_NODES) return;
  const float* hj = h + (size_t)col * D;
  float acc[D];
#pragma unroll
  for (int dd = 0; dd < D; ++dd) acc[dd] = bh[dd];
  float wsum = bx[0];
#pragma unroll 2
  for (int kg = 0; kg < D / 4; ++kg) {
    float4 hv = *(const float4*)(hj + kg * 4);
#pragma unroll
    for (int j = 0; j < 4; ++j) {
      float hk = (j == 0) ? hv.x : (j == 1) ? hv.y : (j == 2) ? hv.z : hv.w;
      int k = kg * 4 + j;
      wsum = fmaf(hk, Wx[k], wsum);
      const float* wrow = Wh + k * D;
#pragma unroll
      for (int dd = 0; dd < D; ++dd) acc[dd] = fmaf(hk, wrow[dd], acc[dd]);
    }
  }
  float* outh = out + (size_t)row * D;
#pragma unroll
  for (int dd = 0; dd < D; ++dd) atomicAdd(&outh[dd], fmaxf(acc[dd], 0.0f));
  float w = fmaxf(wsum, 0.0f);
  float* outx = out + (size_t)N_NODES * D + (size_t)row * 3;
  const float* xr = x + (size_t)row * 3;
  const float* xc = x + (size_t)col * 3;
#pragma unroll
  for (int c = 0; c < 3; ++c) atomicAdd(&outx[c], (xr[c] - xc[c]) * w);
}

// ---------------- launch ----------------

extern "C" void kernel_launch(void* const* d_in, const int* in_sizes, int n_in,
                              void* d_out, int out_size, void* d_ws, size_t ws_size,
                              hipStream_t stream) {
  const float* h    = (const float*)d_in[0];
  const float* x    = (const float*)d_in[1];
  const int*   eidx = (const int*)d_in[2];   // int64 in reference, int32 here
  const float* Wh   = (const float*)d_in[3];
  const float* bh   = (const float*)d_in[4];
  const float* Wx   = (const float*)d_in[5];
  const float* bx   = (const float*)d_in[6];
  float* out = (float*)d_out;

  // workspace: M16 6.4MB | px 0.8MB | bins 3.67MB | gcur 1KB  (~10.9MB)
  size_t need = (size_t)N_NODES * D * 2 + (size_t)N_NODES * 16 +
                (size_t)NBIN * BCAP * 4 + 1024;

  if (ws_size < need) {  // fallback: atomic path (correct, slow)
    const int NT4 = (N_NODES * D + N_NODES * 3) / 4;
    init_out_kernel<<<(NT4 + 255) / 256, 256, 0, stream>>>(h, x, out);
    edge_kernel<<<(N_EDGES + 255) / 256, 256, 0, stream>>>(
        h, x, eidx, Wh, bh, Wx, bx, out);
    return;
  }

  __half2* M16 = (__half2*)d_ws;
  float4*  px  = (float4*)((char*)d_ws + (size_t)N_NODES * D * 2);
  int*     bins = (int*)((char*)px + (size_t)N_NODES * 16);
  int*     gcur = bins + (size_t)NBIN * BCAP;

  hipMemsetAsync(gcur, 0, NBIN * sizeof(int), stream);
  pre_bin_kernel<<<NBINBLK + PREBLK, BLOCK, 0, stream>>>(
      h, x, eidx, Wh, bh, Wx, bx, M16, px, bins, gcur);
  agg_kernel<<<NBIN * SUBS, 256, 0, stream>>>(
      h, x, bins, gcur, M16, px, out);
}

// Round 7
// 127.879 us; speedup vs baseline: 2.3971x; 1.0972x over previous
//
#include <hip/hip_runtime.h>
#include <hip/hip_fp16.h>

#define N_NODES 50000
#define N_EDGES 800000
#define D 64
#define BLOCK 256

#define NBIN 256      // bins over node space
#define BINW 196      // nodes per bin; 256*196 = 50176 >= 50000
#define BCAP 3584     // per-bin capacity; Binom mean 3136, sd 56 -> +8 sigma
#define EPB 4096      // edges per binning block (R4 value; 64B runs, no write amp)
#define NBINBLK 196   // ceil(800000/4096)
#define PREBLK 196    // MLP blocks, 256 nodes each
#define SUBS 8        // agg sub-blocks per bin -> grid 2048 = 8 blocks/CU
#define RNODES 25     // rows per agg block; 8*25=200 >= 196 (tail capped by BINW)
#define QCAP 576      // per-agg-block queue; mean 400, sd 20 -> +8.8 sigma
#define ROWS_PS 2     // rows per 16-lane stream: ceil(25/16)

// ---------- merged binning | precompute (R4-proven) ------------------------
// Binning (blocks [0,196)): counting-sort 4096 edges into 256 node-range bins
// in LDS, write ~64B contiguous runs (no write amplification).
// Precompute (blocks [196,392)): one node per lane, acc[64] register MLP,
// zero cross-lane ops.
__global__ __launch_bounds__(BLOCK) void pre_bin_kernel(
    const float* __restrict__ h, const float* __restrict__ x,
    const int* __restrict__ eidx,
    const float* __restrict__ Wh, const float* __restrict__ bh,
    const float* __restrict__ Wx, const float* __restrict__ bx,
    __half2* __restrict__ M16, float4* __restrict__ px,
    int* __restrict__ bins, int* __restrict__ gcur) {
  const unsigned b = blockIdx.x;

  if (b < NBINBLK) {                   // ---- binning path ----
    __shared__ int cnt[NBIN], ssc[NBIN], start[NBIN], cur[NBIN], gbase[NBIN];
    __shared__ int stage[EPB];         // 16 KB
    const int t = threadIdx.x;
    cnt[t] = 0;
    __syncthreads();
    const int base = (int)b * EPB;
#pragma unroll 4
    for (int k = 0; k < EPB / BLOCK; ++k) {    // pass 1: histogram
      int e = base + k * BLOCK + t;
      if (e < N_EDGES) {
        int row = eidx[e];
        if ((unsigned)row < N_NODES) atomicAdd(&cnt[row / BINW], 1);
      }
    }
    __syncthreads();
    ssc[t] = cnt[t];                   // inclusive prefix scan over 256 bins
    __syncthreads();
    for (int off = 1; off < NBIN; off <<= 1) {
      int v = (t >= off) ? ssc[t - off] : 0;
      __syncthreads();
      ssc[t] += v;
      __syncthreads();
    }
    int ex = ssc[t] - cnt[t];
    start[t] = ex;
    cur[t] = ex;
    gbase[t] = cnt[t] ? atomicAdd(&gcur[t], cnt[t]) : 0;  // one global atomic/bin
    __syncthreads();
#pragma unroll 4
    for (int k = 0; k < EPB / BLOCK; ++k) {    // pass 2: scatter into LDS stage
      int e = base + k * BLOCK + t;
      if (e < N_EDGES) {
        int row = eidx[e];
        int col = eidx[N_EDGES + e];
        if ((unsigned)row < N_NODES && (unsigned)col < N_NODES) {
          int bb = row / BINW;
          int pos = atomicAdd(&cur[bb], 1);
          stage[pos] = (bb << 24) | ((row - bb * BINW) << 16) | col;
        }
      }
    }
    __syncthreads();
    const int total = ssc[NBIN - 1];
    for (int idx = t; idx < total; idx += BLOCK) {  // coalesced run copy-out
      int e = stage[idx];
      int bb = ((unsigned)e) >> 24;
      int dst = gbase[bb] + (idx - start[bb]);
      if (dst < BCAP) bins[(size_t)bb * BCAP + dst] = e;
    }
    return;
  }

  // ---- precompute path: one node per lane, register accumulators ----
  const int pid = (int)b - NBINBLK;    // 0..195
  const int i = pid * BLOCK + threadIdx.x;
  if (i >= N_NODES) return;

  const float4* __restrict__ h4 = (const float4*)(h + (size_t)i * D);
  const float4* __restrict__ Wx4 = (const float4*)Wx;

  float acc[D];
#pragma unroll
  for (int d = 0; d < D; ++d) acc[d] = bh[d];
  float wx = bx[0];

  for (int q = 0; q < D / 4; ++q) {    // NOT unrolled: keeps code ~256 fma
    float4 hv = h4[q];
    float4 wxv = Wx4[q];               // wave-uniform
    wx = fmaf(hv.x, wxv.x, fmaf(hv.y, wxv.y, fmaf(hv.z, wxv.z,
         fmaf(hv.w, wxv.w, wx))));
#pragma unroll
    for (int r = 0; r < 4; ++r) {
      float hk = (r == 0) ? hv.x : (r == 1) ? hv.y : (r == 2) ? hv.z : hv.w;
      const float4* wr4 = (const float4*)(Wh + (q * 4 + r) * D);  // uniform row
#pragma unroll
      for (int dq = 0; dq < D / 4; ++dq) {
        float4 wv = wr4[dq];
        acc[4 * dq + 0] = fmaf(hk, wv.x, acc[4 * dq + 0]);
        acc[4 * dq + 1] = fmaf(hk, wv.y, acc[4 * dq + 1]);
        acc[4 * dq + 2] = fmaf(hk, wv.z, acc[4 * dq + 2]);
        acc[4 * dq + 3] = fmaf(hk, wv.w, acc[4 * dq + 3]);
      }
    }
  }

  __half2 hh[D / 2];
#pragma unroll
  for (int j = 0; j < D / 2; ++j)
    hh[j] = __floats2half2_rn(fmaxf(acc[2 * j], 0.0f),
                              fmaxf(acc[2 * j + 1], 0.0f));
  float4* mrow = (float4*)(M16 + (size_t)i * 32);
  const float4* hhp = (const float4*)hh;
#pragma unroll
  for (int q = 0; q < 8; ++q) mrow[q] = hhp[q];  // per-lane 128B row

  float w = fmaxf(wx, 0.0f);
  px[i] = make_float4(w, w * x[(size_t)i * 3 + 0],
                      w * x[(size_t)i * 3 + 1],
                      w * x[(size_t)i * 3 + 2]);
}

// ---------- aggregate: 8 blocks/bin (2048 blocks = 8/CU, 32 waves/CU) ------
// R6 post-mortem: agg was latency-bound at ~10 GB/s/CU (4 blocks/CU, ~32
// outstanding lines x 64B / ~500cy). Fix = concurrency: SUBS=8 doubles
// resident waves; __launch_bounds__(256,8) pins VGPR<=64 so all 32 waves/CU
// fit. Bin run staged to LDS on pass 1 (pass 2 reads LDS, halves global
// prologue traffic). M-loads issued before px-loads (unbroken 8-deep pipe).
__global__ __launch_bounds__(256, 8) void agg_kernel(
    const float* __restrict__ h, const float* __restrict__ x,
    const int* __restrict__ bins, const int* __restrict__ gcur,
    const __half2* __restrict__ M16, const float4* __restrict__ px,
    float* __restrict__ out) {
  __shared__ int stage2[BCAP];         // 14.3 KB: bin run staged in LDS
  __shared__ int qs[QCAP];             // 2.3 KB
  __shared__ int hist[RNODES], rcur[RNODES];
  __shared__ int rstart[RNODES + 1];

  const int t = threadIdx.x;
  const int bin = blockIdx.x >> 3, sub = blockIdx.x & 7;
  const int lbase = sub * RNODES;      // 0..175
  const int gb = bin * BINW + lbase;   // first global node
  const int R = min(min(RNODES, BINW - lbase), N_NODES - gb);
  if (R <= 0) return;                  // sub=7 tail (21 rows) and node cap

  if (t < RNODES) hist[t] = 0;
  __syncthreads();

  const int n = min(gcur[bin], BCAP);
  const int* bs = bins + (size_t)bin * BCAP;
  for (int i = t; i < n; i += 256) {   // pass 1: stage + histogram
    int e = bs[i];
    stage2[i] = e;
    unsigned dd = (unsigned)((e >> 16) & 0xff) - (unsigned)lbase;
    if (dd < (unsigned)R) atomicAdd(&hist[dd], 1);
  }
  __syncthreads();
  if (t < 64) {                        // wave-0 shfl prefix scan over R<=25 rows
    int myh = (t < R) ? hist[t] : 0;
    int v = myh;
#pragma unroll
    for (int off = 1; off < 64; off <<= 1) {
      int u = __shfl_up(v, off);
      if (t >= off) v += u;
    }
    if (t == 0) rstart[0] = 0;
    if (t < R) { rstart[t + 1] = v; rcur[t] = v - myh; }
  }
  __syncthreads();
  for (int i = t; i < n; i += 256) {   // pass 2: row-sorted scatter (from LDS)
    int e = stage2[i];
    unsigned dd = (unsigned)((e >> 16) & 0xff) - (unsigned)lbase;
    if (dd < (unsigned)R) {
      int pos = atomicAdd(&rcur[dd], 1);
      if (pos < QCAP) qs[pos] = e;
    }
  }
  __syncthreads();

  const float* pxf = (const float*)px;
  const float2* M2 = (const float2*)M16;   // 16 float2 per 128B row
  const int l16 = t & 15;              // lane within 16-lane stream
  const int stream = t >> 4;           // 0..15
  const int wbase = t & 48;            // stream's base lane within the wave
  const size_t xb = (size_t)N_NODES * D;

  float ac[ROWS_PS][4];
  float ps[ROWS_PS];
#pragma unroll
  for (int k = 0; k < ROWS_PS; ++k) {
    ac[k][0] = ac[k][1] = ac[k][2] = ac[k][3] = 0.f;
    ps[k] = 0.f;
  }

#pragma unroll
  for (int k = 0; k < ROWS_PS; ++k) {
    int rr = stream + 16 * k;
    if (rr < R) {
      int beg = min(rstart[rr], QCAP);
      int end = min(rstart[rr + 1], QCAP);
      for (int qi = beg; qi < end; qi += 8) {   // 8-deep load pipeline
        float2 g[8];
        float pv[8];
        bool val[8];
        int cs[8];
#pragma unroll
        for (int j = 0; j < 8; ++j) {           // all M-loads first
          int idx = qi + j;
          val[j] = idx < end;
          int e = qs[val[j] ? idx : beg];       // LDS broadcast per stream
          cs[j] = e & 0xffff;
          if (val[j]) g[j] = M2[(size_t)cs[j] * 16 + l16];  // 8B/lane
        }
#pragma unroll
        for (int j = 0; j < 8; ++j) {           // then px partial loads
          pv[j] = 0.f;
          if (val[j] && l16 < 4) pv[j] = pxf[cs[j] * 4 + l16];
        }
#pragma unroll
        for (int j = 0; j < 8; ++j)
          if (val[j]) {
            const __half2* hp = (const __half2*)&g[j];
            float2 f0 = __half22float2(hp[0]);
            float2 f1 = __half22float2(hp[1]);
            ac[k][0] += f0.x; ac[k][1] += f0.y;
            ac[k][2] += f1.x; ac[k][3] += f1.y;
            ps[k] += pv[j];
          }
      }
    }
  }

#pragma unroll
  for (int k = 0; k < ROWS_PS; ++k) {  // epilogue: exclusive, coalesced
    int rr = stream + 16 * k;
    if (rr < R) {
      int gn = gb + rr;
      float4 hvv = ((const float4*)h)[(size_t)gn * 16 + l16];
      ((float4*)out)[(size_t)gn * 16 + l16] =
          make_float4(hvv.x + ac[k][0], hvv.y + ac[k][1],
                      hvv.z + ac[k][2], hvv.w + ac[k][3]);
      float W = __shfl(ps[k], wbase);            // stream lane0: sum w
      float pc = __shfl(ps[k], wbase + l16 + 1); // lanes 1..3: sum w*x_c
      if (l16 < 3)
        out[xb + (size_t)gn * 3 + l16] =
            fmaf(x[(size_t)gn * 3 + l16], 1.0f + W, -pc);
    }
  }
}

// ---------------- fallback (atomic path, used only if ws too small) --------

__global__ __launch_bounds__(256) void init_out_kernel(
    const float* __restrict__ h, const float* __restrict__ x,
    float* __restrict__ out) {
  const int NH4 = N_NODES * D / 4;
  const int NT4 = (N_NODES * D + N_NODES * 3) / 4;
  int i = blockIdx.x * 256 + threadIdx.x;
  if (i >= NT4) return;
  float4 v;
  if (i < NH4) v = ((const float4*)h)[i];
  else         v = ((const float4*)x)[i - NH4];
  ((float4*)out)[i] = v;
}

__global__ __launch_bounds__(256) void edge_kernel(
    const float* __restrict__ h, const float* __restrict__ x,
    const int* __restrict__ eidx,
    const float* __restrict__ Wh, const float* __restrict__ bh,
    const float* __restrict__ Wx, const float* __restrict__ bx,
    float* __restrict__ out) {
  int e = blockIdx.x * 256 + threadIdx.x;
  if (e >= N_EDGES) return;
  int row = eidx[e];
  int col = eidx[N_EDGES + e];
  if ((unsigned)row >= N_NODES || (unsigned)col >= N_NODES) return;
  const float* hj = h + (size_t)col * D;
  float acc[D];
#pragma unroll
  for (int dd = 0; dd < D; ++dd) acc[dd] = bh[dd];
  float wsum = bx[0];
#pragma unroll 2
  for (int kg = 0; kg < D / 4; ++kg) {
    float4 hv = *(const float4*)(hj + kg * 4);
#pragma unroll
    for (int j = 0; j < 4; ++j) {
      float hk = (j == 0) ? hv.x : (j == 1) ? hv.y : (j == 2) ? hv.z : hv.w;
      int k = kg * 4 + j;
      wsum = fmaf(hk, Wx[k], wsum);
      const float* wrow = Wh + k * D;
#pragma unroll
      for (int dd = 0; dd < D; ++dd) acc[dd] = fmaf(hk, wrow[dd], acc[dd]);
    }
  }
  float* outh = out + (size_t)row * D;
#pragma unroll
  for (int dd = 0; dd < D; ++dd) atomicAdd(&outh[dd], fmaxf(acc[dd], 0.0f));
  float w = fmaxf(wsum, 0.0f);
  float* outx = out + (size_t)N_NODES * D + (size_t)row * 3;
  const float* xr = x + (size_t)row * 3;
  const float* xc = x + (size_t)col * 3;
#pragma unroll
  for (int c = 0; c < 3; ++c) atomicAdd(&outx[c], (xr[c] - xc[c]) * w);
}

// ---------------- launch ----------------

extern "C" void kernel_launch(void* const* d_in, const int* in_sizes, int n_in,
                              void* d_out, int out_size, void* d_ws, size_t ws_size,
                              hipStream_t stream) {
  const float* h    = (const float*)d_in[0];
  const float* x    = (const float*)d_in[1];
  const int*   eidx = (const int*)d_in[2];   // int64 in reference, int32 here
  const float* Wh   = (const float*)d_in[3];
  const float* bh   = (const float*)d_in[4];
  const float* Wx   = (const float*)d_in[5];
  const float* bx   = (const float*)d_in[6];
  float* out = (float*)d_out;

  // workspace: M16 6.4MB | px 0.8MB | bins 3.67MB | gcur 1KB  (~10.9MB)
  size_t need = (size_t)N_NODES * D * 2 + (size_t)N_NODES * 16 +
                (size_t)NBIN * BCAP * 4 + 1024;

  if (ws_size < need) {  // fallback: atomic path (correct, slow)
    const int NT4 = (N_NODES * D + N_NODES * 3) / 4;
    init_out_kernel<<<(NT4 + 255) / 256, 256, 0, stream>>>(h, x, out);
    edge_kernel<<<(N_EDGES + 255) / 256, 256, 0, stream>>>(
        h, x, eidx, Wh, bh, Wx, bx, out);
    return;
  }

  __half2* M16 = (__half2*)d_ws;
  float4*  px  = (float4*)((char*)d_ws + (size_t)N_NODES * D * 2);
  int*     bins = (int*)((char*)px + (size_t)N_NODES * 16);
  int*     gcur = bins + (size_t)NBIN * BCAP;

  hipMemsetAsync(gcur, 0, NBIN * sizeof(int), stream);
  pre_bin_kernel<<<NBINBLK + PREBLK, BLOCK, 0, stream>>>(
      h, x, eidx, Wh, bh, Wx, bx, M16, px, bins, gcur);
  agg_kernel<<<NBIN * SUBS, 256, 0, stream>>>(
      h, x, bins, gcur, M16, px, out);
}